// Round 2
// baseline (208.805 us; speedup 1.0000x reference)
//
#include <hip/hip_runtime.h>
#include <stdint.h>

#define NROW 8192
#define DIM  512
#define NOUT 16
#define GAMMA 0.001f
// exp(2*gamma*c) = exp2(c * 2*gamma*log2(e))
#define EXP2S (2.0f * GAMMA * 1.44269504088896340736f)

typedef __bf16 bf16_t;
typedef bf16_t bf16x4_t __attribute__((ext_vector_type(4)));
typedef bf16_t bf16x8_t __attribute__((ext_vector_type(8)));
typedef float  floatx4_t __attribute__((ext_vector_type(4)));

// async global->LDS, 16 B/lane. LDS dest is wave-uniform base + lane*16.
__device__ __forceinline__ void async_copy16(const void* g, const void* l) {
    __builtin_amdgcn_global_load_lds(
        (__attribute__((address_space(1))) void*)(uintptr_t)g,
        (__attribute__((address_space(3))) void*)(uint32_t)(uintptr_t)l,
        16, 0, 0);
}

// ---------- prep 1: fp32 -> bf16 rows + exp(-gamma*||row||^2) factors ----------
__global__ __launch_bounds__(256) void prep_convert(
    const float* __restrict__ X, const float* __restrict__ T,
    bf16_t* __restrict__ Xb, bf16_t* __restrict__ Tb,
    float* __restrict__ xfac, float* __restrict__ yfac)
{
    const int w = threadIdx.x >> 6, lane = threadIdx.x & 63;
    const int row = blockIdx.x * 4 + w;              // 0..16383
    const float* src; bf16_t* dst; float* fac; int r;
    if (row < NROW) { src = X; dst = Xb; fac = xfac; r = row; }
    else           { src = T; dst = Tb; fac = yfac; r = row - NROW; }
    const float4* s4 = (const float4*)(src + (size_t)r * DIM);
    const float4 v0 = s4[lane];
    const float4 v1 = s4[lane + 64];
    float ss = v0.x*v0.x + v0.y*v0.y + v0.z*v0.z + v0.w*v0.w
             + v1.x*v1.x + v1.y*v1.y + v1.z*v1.z + v1.w*v1.w;
    bf16x4_t o0 = { (bf16_t)v0.x, (bf16_t)v0.y, (bf16_t)v0.z, (bf16_t)v0.w };
    bf16x4_t o1 = { (bf16_t)v1.x, (bf16_t)v1.y, (bf16_t)v1.z, (bf16_t)v1.w };
    bf16x4_t* d4 = (bf16x4_t*)(dst + (size_t)r * DIM);
    d4[lane] = o0;
    d4[lane + 64] = o1;
#pragma unroll
    for (int m = 32; m > 0; m >>= 1) ss += __shfl_xor(ss, m, 64);
    if (lane == 0) fac[r] = __expf(-GAMMA * ss);
}

// ---------- prep 2: alphaT'[o][j] = bf16( exp(-g*||y_j||^2) * alpha[j][o] ) ----------
__global__ __launch_bounds__(256) void prep_alpha(
    const float* __restrict__ alpha, const float* __restrict__ yfac,
    bf16_t* __restrict__ alphaTp)
{
    const int t = blockIdx.x * 256 + threadIdx.x;    // 131072
    const int j = t >> 4, o = t & 15;
    alphaTp[(size_t)o * NROW + j] = (bf16_t)(alpha[t] * yfac[j]);
}

// ---------- main: 128x128 bf16 MFMA GEMM + fused exp + @alpha' epilogue ----------
// Roles: M = train (A operand), N = test (B operand). C-layout lane then owns
// 4 consecutive TRAIN rows x 1 test col -> 8B K'' stores, contiguous epilogue A-reads.
#define BK 32
#define TPT 4        // train tiles per block (16 chunks x 4 tiles = 8192)
#define KLD2 72      // padded row stride (bf16) of per-wave K'' tile [test 64][train 64]

__global__ __launch_bounds__(256, 4) void rbf_main(
    const bf16_t* __restrict__ Xb, const bf16_t* __restrict__ Tb,
    const bf16_t* __restrict__ alphaTp, const float* __restrict__ xfac,
    float* __restrict__ out)
{
    // union: staging Ts[128][32](8KB)+Xs[128][32](8KB)  vs  4 waves x K''[64][72]
    __shared__ __align__(16) unsigned char smem[4 * 64 * KLD2 * 2];

    const int tid = threadIdx.x;
    const int w = tid >> 6, lane = tid & 63;
    const int wm = w >> 1, wn = w & 1;               // train half / test half
    const int quad = lane >> 4, l15 = lane & 15;

    const int rb = blockIdx.y;                       // 0..63   test block
    const int chunk = blockIdx.x;                    // 0..15   train chunk
    const int row0 = rb * 128;                       // test base row

    // staging slot: s = tid (+256 for 2nd issue); row = s>>2, col16 = (s&3) ^ ((row>>1)&3)
    const int s_row = tid >> 2;
    const int s_colb = (((tid & 3) ^ ((s_row >> 1) & 3)) * 16);
    const char* gX = (const char*)(Xb + (size_t)(row0 + s_row) * DIM) + s_colb;
    const unsigned ldsW = (unsigned)(w << 10);       // wave-uniform LDS base

    // frag-read swizzle: row r -> byte r*64 + ((quad ^ ((r>>1)&3))*16); here
    // (r>>1)&3 == (l15>>1)&3 for all our rows (offsets are multiples of 16)
    const int xsw = ((quad ^ ((l15 >> 1) & 3)) * 16);

    const floatx4_t vzero = {0.f, 0.f, 0.f, 0.f};
    floatx4_t oacc[4];
#pragma unroll
    for (int i = 0; i < 4; ++i) oacc[i] = vzero;

    bf16_t* kw = (bf16_t*)smem + w * (64 * KLD2);    // this wave's K'' region

    for (int t = 0; t < TPT; ++t) {
        const int cb = chunk * (TPT * 128) + t * 128;    // train base row
        const char* gT = (const char*)(Tb + (size_t)(cb + s_row) * DIM) + s_colb;

        floatx4_t acc[4][4];
#pragma unroll
        for (int i = 0; i < 4; ++i)
#pragma unroll
            for (int j = 0; j < 4; ++j) acc[i][j] = vzero;

        for (int kb = 0; kb < DIM * 2; kb += BK * 2) {   // byte offset along K
            __syncthreads();                             // prev LDS reads done
            async_copy16(gT + kb,           smem + ldsW);          // train rows 0..63
            async_copy16(gT + 65536 + kb,   smem + 4096 + ldsW);   // train rows 64..127
            async_copy16(gX + kb,           smem + 8192 + ldsW);   // test rows 0..63
            async_copy16(gX + 65536 + kb,   smem + 12288 + ldsW);  // test rows 64..127
            __syncthreads();                             // drains vmcnt: loads landed

            bf16x8_t af[4], bfv[4];
#pragma unroll
            for (int i = 0; i < 4; ++i) {
                const int ra = wm * 64 + i * 16 + l15;       // train row
                const int rbn = wn * 64 + i * 16 + l15;      // test row
                af[i]  = *(const bf16x8_t*)(smem + ra * 64 + xsw);
                bfv[i] = *(const bf16x8_t*)(smem + 8192 + rbn * 64 + xsw);
            }
#pragma unroll
            for (int mi = 0; mi < 4; ++mi)
#pragma unroll
                for (int ni = 0; ni < 4; ++ni)
                    acc[mi][ni] = __builtin_amdgcn_mfma_f32_16x16x32_bf16(
                        af[mi], bfv[ni], acc[mi][ni], 0, 0, 0);
        }

        __syncthreads();   // all frag reads of Ts/Xs done before overwrite with K''
        // K'' = exp(2*gamma*cross), bf16, test-major: kw[test][train], 8B packed stores
        // acc[mi][ni][r] = cross[train = mi*16+quad*4+r][test = ni*16+l15]
#pragma unroll
        for (int ni = 0; ni < 4; ++ni)
#pragma unroll
            for (int mi = 0; mi < 4; ++mi) {
                bf16x4_t pk;
#pragma unroll
                for (int r = 0; r < 4; ++r)
                    pk[r] = (bf16_t)__builtin_amdgcn_exp2f(acc[mi][ni][r] * EXP2S);
                *(bf16x4_t*)(kw + (ni * 16 + l15) * KLD2 + mi * 16 + quad * 4) = pk;
            }
        // no barrier: each wave reads only its own kw region (in-wave lgkmcnt orders)

        // epilogue: oacc[ni] += K''[test 16(ni) x train 64] @ alpha'[train 64 x o 16]
#pragma unroll
        for (int ks = 0; ks < 2; ++ks) {
            const bf16x8_t bv = *(const bf16x8_t*)(alphaTp + (size_t)l15 * NROW
                                                   + cb + wm * 64 + ks * 32 + quad * 8);
#pragma unroll
            for (int ni = 0; ni < 4; ++ni) {
                const bf16x8_t av = *(const bf16x8_t*)(kw + (ni * 16 + l15) * KLD2
                                                       + ks * 32 + quad * 8);
                oacc[ni] = __builtin_amdgcn_mfma_f32_16x16x32_bf16(av, bv, oacc[ni], 0, 0, 0);
            }
        }
        // next t: leading __syncthreads() protects kw reads vs restaging
    }

    // reduce the two train halves (wm=0,1) through LDS, then atomicAdd to out
    __syncthreads();
    float* stash = (float*)smem;
    if (wm == 1) {
#pragma unroll
        for (int ni = 0; ni < 4; ++ni)
            *(floatx4_t*)(stash + wn * 1024 + ni * 256 + lane * 4) = oacc[ni];
    }
    __syncthreads();
    if (wm == 0) {
#pragma unroll
        for (int ni = 0; ni < 4; ++ni) {
            const floatx4_t o2 = *(const floatx4_t*)(stash + wn * 1024 + ni * 256 + lane * 4);
            const int trow = row0 + wn * 64 + ni * 16 + quad * 4;
            const float4 xf = *(const float4*)(xfac + trow);
            atomicAdd(out + (size_t)(trow + 0) * NOUT + l15, (oacc[ni][0] + o2[0]) * xf.x);
            atomicAdd(out + (size_t)(trow + 1) * NOUT + l15, (oacc[ni][1] + o2[1]) * xf.y);
            atomicAdd(out + (size_t)(trow + 2) * NOUT + l15, (oacc[ni][2] + o2[2]) * xf.z);
            atomicAdd(out + (size_t)(trow + 3) * NOUT + l15, (oacc[ni][3] + o2[3]) * xf.w);
        }
    }
}

extern "C" void kernel_launch(void* const* d_in, const int* in_sizes, int n_in,
                              void* d_out, int out_size, void* d_ws, size_t ws_size,
                              hipStream_t stream) {
    (void)in_sizes; (void)n_in; (void)out_size; (void)ws_size;
    const float* X     = (const float*)d_in[0];
    const float* T     = (const float*)d_in[1];
    const float* alpha = (const float*)d_in[2];

    char* ws = (char*)d_ws;
    bf16_t* Xb      = (bf16_t*)ws;                                   // 8 MB
    bf16_t* Tb      = (bf16_t*)(ws + (8u << 20));                    // 8 MB
    float*  xfac    = (float*)(ws + (16u << 20));                    // 32 KB
    float*  yfac    = (float*)(ws + (16u << 20) + (32u << 10));      // 32 KB
    bf16_t* alphaTp = (bf16_t*)(ws + (16u << 20) + (64u << 10));     // 256 KB
    float*  out     = (float*)d_out;

    hipMemsetAsync(out, 0, (size_t)NROW * NOUT * sizeof(float), stream);
    prep_convert<<<4096, 256, 0, stream>>>(X, T, Xb, Tb, xfac, yfac);
    prep_alpha<<<512, 256, 0, stream>>>(alpha, yfac, alphaTp);
    dim3 grid(16, 64);
    rbf_main<<<grid, 256, 0, stream>>>(Xb, Tb, alphaTp, xfac, out);
}

// Round 3
// 195.926 us; speedup vs baseline: 1.0657x; 1.0657x over previous
//
#include <hip/hip_runtime.h>
#include <stdint.h>

#define NROW 8192
#define DIM  512
#define NOUT 16
#define GAMMA 0.001f
// exp(2*gamma*c) = exp2(c * 2*gamma*log2(e))
#define EXP2S (2.0f * GAMMA * 1.44269504088896340736f)

typedef __bf16 bf16_t;
typedef bf16_t bf16x4_t __attribute__((ext_vector_type(4)));
typedef bf16_t bf16x8_t __attribute__((ext_vector_type(8)));
typedef float  floatx4_t __attribute__((ext_vector_type(4)));

// async global->LDS, 16 B/lane. LDS dest is wave-uniform base + lane*16.
__device__ __forceinline__ void async_copy16(const void* g, const void* l) {
    __builtin_amdgcn_global_load_lds(
        (__attribute__((address_space(1))) void*)(uintptr_t)g,
        (__attribute__((address_space(3))) void*)(uint32_t)(uintptr_t)l,
        16, 0, 0);
}

// ---------- prep 1: fp32 -> bf16 rows + exp(-gamma*||row||^2) factors ----------
__global__ __launch_bounds__(256) void prep_convert(
    const float* __restrict__ X, const float* __restrict__ T,
    bf16_t* __restrict__ Xb, bf16_t* __restrict__ Tb,
    float* __restrict__ xfac, float* __restrict__ yfac)
{
    const int w = threadIdx.x >> 6, lane = threadIdx.x & 63;
    const int row = blockIdx.x * 4 + w;              // 0..16383
    const float* src; bf16_t* dst; float* fac; int r;
    if (row < NROW) { src = X; dst = Xb; fac = xfac; r = row; }
    else           { src = T; dst = Tb; fac = yfac; r = row - NROW; }
    const float4* s4 = (const float4*)(src + (size_t)r * DIM);
    const float4 v0 = s4[lane];
    const float4 v1 = s4[lane + 64];
    float ss = v0.x*v0.x + v0.y*v0.y + v0.z*v0.z + v0.w*v0.w
             + v1.x*v1.x + v1.y*v1.y + v1.z*v1.z + v1.w*v1.w;
    bf16x4_t o0 = { (bf16_t)v0.x, (bf16_t)v0.y, (bf16_t)v0.z, (bf16_t)v0.w };
    bf16x4_t o1 = { (bf16_t)v1.x, (bf16_t)v1.y, (bf16_t)v1.z, (bf16_t)v1.w };
    bf16x4_t* d4 = (bf16x4_t*)(dst + (size_t)r * DIM);
    d4[lane] = o0;
    d4[lane + 64] = o1;
#pragma unroll
    for (int m = 32; m > 0; m >>= 1) ss += __shfl_xor(ss, m, 64);
    if (lane == 0) fac[r] = __expf(-GAMMA * ss);
}

// ---------- prep 2: alphaT'[o][j] = bf16( exp(-g*||y_j||^2) * alpha[j][o] ) ----------
__global__ __launch_bounds__(256) void prep_alpha(
    const float* __restrict__ alpha, const float* __restrict__ yfac,
    bf16_t* __restrict__ alphaTp)
{
    const int t = blockIdx.x * 256 + threadIdx.x;    // 131072
    const int j = t >> 4, o = t & 15;
    alphaTp[(size_t)o * NROW + j] = (bf16_t)(alpha[t] * yfac[j]);
}

// ---------- main: 128x128 bf16 MFMA GEMM + fused exp + @alpha' epilogue ----------
// Roles: M = train (A operand), N = test (B operand).
// Grid: blockIdx.x = rb (test block) so XCD = rb%8 -> per-XCD X slice is
// L2-resident (1 MB) while T streams; blockIdx.y = chunk.
// BK=64: 32 MFMA per barrier-pair (half the vmcnt(0) drains of BK=32).
#define BK 64
#define TPT 4        // train tiles per block (16 chunks x 4 tiles = 8192)
#define KLD2 72      // padded row stride (bf16) of per-wave K'' tile [test 64][train 64]

__global__ __launch_bounds__(256, 4) void rbf_main(
    const bf16_t* __restrict__ Xb, const bf16_t* __restrict__ Tb,
    const bf16_t* __restrict__ alphaTp, const float* __restrict__ xfac,
    float* __restrict__ out)
{
    // union: staging Ts[128][64](16KB)+Xs[128][64](16KB)  vs  4 waves x K''[64][72]
    __shared__ __align__(16) unsigned char smem[4 * 64 * KLD2 * 2];   // 36864 B

    const int tid = threadIdx.x;
    const int w = tid >> 6, lane = tid & 63;
    const int wm = w >> 1, wn = w & 1;               // train half / test half
    const int quad = lane >> 4, l15 = lane & 15;

    const int rb = blockIdx.x;                       // 0..63   test block (XCD affinity)
    const int chunk = blockIdx.y;                    // 0..15   train chunk
    const int row0 = rb * 128;                       // test base row

    // staging slot s = tid + i*256: row = i*32 + (tid>>3), LDS col16 = tid&7,
    // global col16 = (tid&7) ^ (row&7)   (XOR swizzle; row&7 == (tid>>3)&7)
    const int s_row = tid >> 3;                      // 0..31
    const int g_colb = (((tid & 7) ^ (s_row & 7)) * 16);
    const char* gX = (const char*)(Xb + (size_t)(row0 + s_row) * DIM) + g_colb;
    const unsigned ldsW = (unsigned)(w << 10);       // wave base within each 4KB issue-slab

    const floatx4_t vzero = {0.f, 0.f, 0.f, 0.f};
    floatx4_t oacc[4];
#pragma unroll
    for (int i = 0; i < 4; ++i) oacc[i] = vzero;

    bf16_t* kw = (bf16_t*)smem + w * (64 * KLD2);    // this wave's K'' region

    for (int t = 0; t < TPT; ++t) {
        const int cb = chunk * (TPT * 128) + t * 128;    // train base row
        const char* gT = (const char*)(Tb + (size_t)(cb + s_row) * DIM) + g_colb;

        floatx4_t acc[4][4];
#pragma unroll
        for (int i = 0; i < 4; ++i)
#pragma unroll
            for (int j = 0; j < 4; ++j) acc[i][j] = vzero;

        for (int kb = 0; kb < DIM * 2; kb += BK * 2) {   // byte offset along K: 8 iters
            __syncthreads();                             // prev LDS reads done
#pragma unroll
            for (int i = 0; i < 4; ++i) {
                async_copy16(gT + (size_t)i * 32768 + kb, smem + i * 4096 + ldsW);
                async_copy16(gX + (size_t)i * 32768 + kb, smem + 16384 + i * 4096 + ldsW);
            }
            __syncthreads();                             // drains vmcnt: loads landed

            // two k-halves of 32; frag for k-half h at global col16 g = h*4+quad,
            // physical col16 p = g ^ (row&7), row&7 == l15&7 here
#pragma unroll
            for (int h = 0; h < 2; ++h) {
                const int xs = (((h * 4 + quad) ^ (l15 & 7)) * 16);
                bf16x8_t af[4], bfv[4];
#pragma unroll
                for (int i = 0; i < 4; ++i) {
                    af[i]  = *(const bf16x8_t*)(smem + (wm * 64 + i * 16 + l15) * 128 + xs);
                    bfv[i] = *(const bf16x8_t*)(smem + 16384 + (wn * 64 + i * 16 + l15) * 128 + xs);
                }
#pragma unroll
                for (int mi = 0; mi < 4; ++mi)
#pragma unroll
                    for (int ni = 0; ni < 4; ++ni)
                        acc[mi][ni] = __builtin_amdgcn_mfma_f32_16x16x32_bf16(
                            af[mi], bfv[ni], acc[mi][ni], 0, 0, 0);
            }
        }

        __syncthreads();   // all frag reads of Ts/Xs done before overwrite with K''
        // K'' = exp(2*gamma*cross), bf16, test-major: kw[test][train], 8B packed stores
        // acc[mi][ni][r] = cross[train = mi*16+quad*4+r][test = ni*16+l15]
#pragma unroll
        for (int ni = 0; ni < 4; ++ni)
#pragma unroll
            for (int mi = 0; mi < 4; ++mi) {
                bf16x4_t pk;
#pragma unroll
                for (int r = 0; r < 4; ++r)
                    pk[r] = (bf16_t)__builtin_amdgcn_exp2f(acc[mi][ni][r] * EXP2S);
                *(bf16x4_t*)(kw + (ni * 16 + l15) * KLD2 + mi * 16 + quad * 4) = pk;
            }
        // no barrier: each wave reads only its own kw region (in-wave lgkmcnt orders)

        // epilogue: oacc[ni] += K''[test 16(ni) x train 64] @ alpha'[train 64 x o 16]
#pragma unroll
        for (int ks = 0; ks < 2; ++ks) {
            const bf16x8_t bv = *(const bf16x8_t*)(alphaTp + (size_t)l15 * NROW
                                                   + cb + wm * 64 + ks * 32 + quad * 8);
#pragma unroll
            for (int ni = 0; ni < 4; ++ni) {
                const bf16x8_t av = *(const bf16x8_t*)(kw + (ni * 16 + l15) * KLD2
                                                       + ks * 32 + quad * 8);
                oacc[ni] = __builtin_amdgcn_mfma_f32_16x16x32_bf16(av, bv, oacc[ni], 0, 0, 0);
            }
        }
        // next t: leading __syncthreads() protects kw reads vs restaging
    }

    // reduce the two train halves (wm=0,1) through LDS, then atomicAdd to out
    __syncthreads();
    float* stash = (float*)smem;
    if (wm == 1) {
#pragma unroll
        for (int ni = 0; ni < 4; ++ni)
            *(floatx4_t*)(stash + wn * 1024 + ni * 256 + lane * 4) = oacc[ni];
    }
    __syncthreads();
    if (wm == 0) {
#pragma unroll
        for (int ni = 0; ni < 4; ++ni) {
            const floatx4_t o2 = *(const floatx4_t*)(stash + wn * 1024 + ni * 256 + lane * 4);
            const int trow = row0 + wn * 64 + ni * 16 + quad * 4;
            const float4 xf = *(const float4*)(xfac + trow);
            atomicAdd(out + (size_t)(trow + 0) * NOUT + l15, (oacc[ni][0] + o2[0]) * xf.x);
            atomicAdd(out + (size_t)(trow + 1) * NOUT + l15, (oacc[ni][1] + o2[1]) * xf.y);
            atomicAdd(out + (size_t)(trow + 2) * NOUT + l15, (oacc[ni][2] + o2[2]) * xf.z);
            atomicAdd(out + (size_t)(trow + 3) * NOUT + l15, (oacc[ni][3] + o2[3]) * xf.w);
        }
    }
}

extern "C" void kernel_launch(void* const* d_in, const int* in_sizes, int n_in,
                              void* d_out, int out_size, void* d_ws, size_t ws_size,
                              hipStream_t stream) {
    (void)in_sizes; (void)n_in; (void)out_size; (void)ws_size;
    const float* X     = (const float*)d_in[0];
    const float* T     = (const float*)d_in[1];
    const float* alpha = (const float*)d_in[2];

    char* ws = (char*)d_ws;
    bf16_t* Xb      = (bf16_t*)ws;                                   // 8 MB
    bf16_t* Tb      = (bf16_t*)(ws + (8u << 20));                    // 8 MB
    float*  xfac    = (float*)(ws + (16u << 20));                    // 32 KB
    float*  yfac    = (float*)(ws + (16u << 20) + (32u << 10));      // 32 KB
    bf16_t* alphaTp = (bf16_t*)(ws + (16u << 20) + (64u << 10));     // 256 KB
    float*  out     = (float*)d_out;

    hipMemsetAsync(out, 0, (size_t)NROW * NOUT * sizeof(float), stream);
    prep_convert<<<4096, 256, 0, stream>>>(X, T, Xb, Tb, xfac, yfac);
    prep_alpha<<<512, 256, 0, stream>>>(alpha, yfac, alphaTp);
    dim3 grid(64, 16);   // x = rb (XCD affinity for X), y = chunk
    rbf_main<<<grid, 256, 0, stream>>>(Xb, Tb, alphaTp, xfac, out);
}